// Round 7
// baseline (162.527 us; speedup 1.0000x reference)
//
#include <hip/hip_runtime.h>

using f16   = _Float16;
using f16x4 = __attribute__((ext_vector_type(4))) _Float16;
using f16x8 = __attribute__((ext_vector_type(8))) _Float16;
using f32x4 = __attribute__((ext_vector_type(4))) float;

#define BDIM 4
#define EDIM 512
#define LDIM 512
#define VDIM 32000
#define RDIM 2048            // B*L
#define INV_TAU 0.1f

using gcvoid = const __attribute__((address_space(1))) void;
using lvoid  = __attribute__((address_space(3))) void;

__device__ __forceinline__ void gload_lds16(const void* g, void* l) {
  __builtin_amdgcn_global_load_lds((gcvoid*)g, (lvoid*)l, 16, 0, 0);
}

// fused HW barrier + compiler memory fence (no hardware waitcnt!)
#define BARRIER() asm volatile("s_barrier" ::: "memory")

// ---------------- kernel 1: DE [B,E,L] f32 -> A16 [R=B*L][E] f16 (transpose+convert)
__global__ void cvtA_kernel(const float* __restrict__ DE, f16* __restrict__ A16) {
  __shared__ float tile[64][65];
  const int b  = blockIdx.z;
  const int e0 = blockIdx.y * 64;
  const int l0 = blockIdx.x * 64;
  const int t  = threadIdx.x;
#pragma unroll
  for (int i = 0; i < 4; ++i) {
    int idx = t + i * 256;
    int el  = idx >> 4;
    int l4  = (idx & 15) * 4;
    float4 v = *reinterpret_cast<const float4*>(
        DE + (size_t)(b * 512 + e0 + el) * 512 + l0 + l4);
    tile[el][l4 + 0] = v.x;
    tile[el][l4 + 1] = v.y;
    tile[el][l4 + 2] = v.z;
    tile[el][l4 + 3] = v.w;
  }
  __syncthreads();
#pragma unroll
  for (int i = 0; i < 4; ++i) {
    int idx = t + i * 256;
    int ll  = idx >> 4;
    int e4  = (idx & 15) * 4;
    f16x4 h;
    h[0] = (f16)tile[e4 + 0][ll];
    h[1] = (f16)tile[e4 + 1][ll];
    h[2] = (f16)tile[e4 + 2][ll];
    h[3] = (f16)tile[e4 + 3][ll];
    *reinterpret_cast<f16x4*>(A16 + (size_t)(b * 512 + l0 + ll) * 512 + e0 + e4) = h;
  }
}

// ---------------- kernel 2: M [V,E] f32 -> B16 [V][E] f16 (stream convert)
__global__ void cvtM_kernel(const float* __restrict__ M, f16* __restrict__ B16) {
  const size_t N4 = (size_t)VDIM * EDIM / 4;
  const size_t stride = (size_t)gridDim.x * blockDim.x;
  for (size_t i = (size_t)blockIdx.x * blockDim.x + threadIdx.x; i < N4; i += stride) {
    float4 v = reinterpret_cast<const float4*>(M)[i];
    f16x4 h = { (f16)v.x, (f16)v.y, (f16)v.z, (f16)v.w };
    reinterpret_cast<f16x4*>(B16)[i] = h;
  }
}

// ---------------- kernel 3: fused GEMM + exp + vocab-sum, 8-phase (hardened)
// Block 256x256, 8 waves (2x4), wave tile 128x64, BK=64, 8 K-tiles.
// LDS 128KB: A[par][kh][256][32] | B[par][kh][256][32], half-slot 16KB.
// 4 phases/K-tile = (khalf, mi-half), 16 MFMA each; staging of T+1 spread
// p1->A.k0 p2->B.k0 p3->A.k1 p4->B.k1 (2 gload_lds/thread each).
// vmcnt(4) at phases 2,4 only (proves the half needed next phase landed;
// 4 loads in flight across barriers). #pragma unroll 1 + peeled last tile
// keeps pressure low (no scratch -> counted-vmcnt ledger stays exact).
// Granule swizzle both sides (R3/R5-verified): granule g of row r = k-chunk
// g ^ ((r>>1)&3). All barriers are compiler memory fences.
__global__ __launch_bounds__(512, 2) void gemm_kernel(const f16* __restrict__ A16,
                                                      const f16* __restrict__ B16,
                                                      float* __restrict__ down) {
  __shared__ __align__(16) char sm[131072];
  const int orig = blockIdx.x;                  // 1000 = 8 * 125
  const int wgid = (orig & 7) * 125 + (orig >> 3);
  const int rt   = wgid & 7;                    // 8 row tiles of 256
  const int ct   = wgid >> 3;                   // 125 col tiles of 256
  const int r0   = rt * 256, c0 = ct * 256;
  const int tid  = threadIdx.x;
  const int lane = tid & 63;
  const int w    = tid >> 6;                    // 0..7
  const int wr   = w >> 2, wc = w & 3;          // 2 x 4 wave grid

  const int srow = lane >> 2;                   // staging row within 16-row group
  const int sel  = ((lane & 3) ^ ((lane >> 3) & 3)) * 8;   // swizzled src granule

  auto stageA = [&](int par, int kh, int T) {
    const int base  = (par * 2 + kh) * 16384;
    const int kbase = T * 64 + kh * 32;
#pragma unroll
    for (int s = 0; s < 2; ++s) {
      int I = w * 2 + s;
      gload_lds16(A16 + (size_t)(r0 + I * 16 + srow) * 512 + kbase + sel,
                  &sm[base + I * 1024]);
    }
  };
  auto stageB = [&](int par, int kh, int T) {
    const int base  = 65536 + (par * 2 + kh) * 16384;
    const int kbase = T * 64 + kh * 32;
#pragma unroll
    for (int s = 0; s < 2; ++s) {
      int I = w * 2 + s;
      gload_lds16(B16 + (size_t)(c0 + I * 16 + srow) * 512 + kbase + sel,
                  &sm[base + I * 1024]);
    }
  };

  f32x4 acc[8][4] = {};

  // prologue: stage all 4 halves of T0; wait k0 halves (youngest 4 = k1 halves)
  stageA(0, 0, 0); stageB(0, 0, 0); stageA(0, 1, 0); stageB(0, 1, 0);
  asm volatile("s_waitcnt vmcnt(4)" ::: "memory");
  BARRIER();

  const int koff = ((lane >> 4) ^ ((lane >> 1) & 3)) * 16;
  const int arow = (wr * 128 + (lane & 15)) * 64 + koff;  // + mi*1024
  const int brow = (wc * 64 + (lane & 15)) * 64 + koff;   // + ni*1024

  f16x8 af[4], bf[4];

#define DS_READ_B(slot)                                                     \
  _Pragma("unroll") for (int n = 0; n < 4; ++n)                             \
      bf[n] = *reinterpret_cast<const f16x8*>(&sm[(slot) + brow + n * 1024]);
#define DS_READ_A(slot, mh)                                                 \
  _Pragma("unroll") for (int m = 0; m < 4; ++m)                             \
      af[m] = *reinterpret_cast<const f16x8*>(                              \
          &sm[(slot) + arow + ((mh) * 4 + m) * 1024]);
#define MFMA_HALF(mh)                                                       \
  asm volatile("s_waitcnt lgkmcnt(0)" ::: "memory");                        \
  __builtin_amdgcn_sched_barrier(0);                                        \
  __builtin_amdgcn_s_setprio(1);                                            \
  _Pragma("unroll") for (int m = 0; m < 4; ++m)                             \
    _Pragma("unroll") for (int n = 0; n < 4; ++n)                           \
      acc[(mh) * 4 + m][n] = __builtin_amdgcn_mfma_f32_16x16x32_f16(        \
          af[m], bf[n], acc[(mh) * 4 + m][n], 0, 0, 0);                     \
  __builtin_amdgcn_s_setprio(0)

#pragma unroll 1
  for (int T = 0; T < 7; ++T) {
    const int par = T & 1, npar = par ^ 1;
    const int Ab0 = (par * 2 + 0) * 16384, Ab1 = (par * 2 + 1) * 16384;
    const int Bb0 = 65536 + (par * 2 + 0) * 16384, Bb1 = 65536 + (par * 2 + 1) * 16384;

    // phase 1: (k0, mi 0-3); stage A.k0 of T+1
    DS_READ_B(Bb0);
    DS_READ_A(Ab0, 0);
    stageA(npar, 0, T + 1);
    BARRIER();
    MFMA_HALF(0);
    BARRIER();

    // phase 2: (k0, mi 4-7); stage B.k0 of T+1; prove k1 of T landed
    DS_READ_A(Ab0, 1);
    stageB(npar, 0, T + 1);
    asm volatile("s_waitcnt vmcnt(4)" ::: "memory");
    BARRIER();
    MFMA_HALF(1);
    BARRIER();

    // phase 3: (k1, mi 0-3); stage A.k1 of T+1
    DS_READ_B(Bb1);
    DS_READ_A(Ab1, 0);
    stageA(npar, 1, T + 1);
    BARRIER();
    MFMA_HALF(0);
    BARRIER();

    // phase 4: (k1, mi 4-7); stage B.k1 of T+1; prove k0 of T+1 landed
    DS_READ_A(Ab1, 1);
    stageB(npar, 1, T + 1);
    asm volatile("s_waitcnt vmcnt(4)" ::: "memory");
    BARRIER();
    MFMA_HALF(1);
    BARRIER();
  }

  // peeled T=7 (par=1): no staging; drain remaining loads before k1 phases
  {
    const int Ab0 = 2 * 16384, Ab1 = 3 * 16384;
    const int Bb0 = 65536 + 2 * 16384, Bb1 = 65536 + 3 * 16384;

    DS_READ_B(Bb0);
    DS_READ_A(Ab0, 0);
    BARRIER();
    MFMA_HALF(0);
    BARRIER();

    DS_READ_A(Ab0, 1);
    asm volatile("s_waitcnt vmcnt(0)" ::: "memory");  // T6-staged k1 halves landed
    BARRIER();
    MFMA_HALF(1);
    BARRIER();

    DS_READ_B(Bb1);
    DS_READ_A(Ab1, 0);
    BARRIER();
    MFMA_HALF(0);
    BARRIER();

    DS_READ_A(Ab1, 1);
    BARRIER();
    MFMA_HALF(1);
  }

  // epilogue: exp + sum over this wave's 64 columns, then atomic into down[]
  // D layout: col = lane&15, row = (lane>>4)*4 + j  (m89-verified)
  const int rbase = r0 + wr * 128;
#pragma unroll
  for (int mi = 0; mi < 8; ++mi) {
    float s0 = 0.f, s1 = 0.f, s2 = 0.f, s3 = 0.f;
#pragma unroll
    for (int ni = 0; ni < 4; ++ni) {
      f32x4 v = acc[mi][ni];
      s0 += __expf(INV_TAU * v[0]);
      s1 += __expf(INV_TAU * v[1]);
      s2 += __expf(INV_TAU * v[2]);
      s3 += __expf(INV_TAU * v[3]);
    }
#pragma unroll
    for (int m = 1; m <= 8; m <<= 1) {
      s0 += __shfl_xor(s0, m);
      s1 += __shfl_xor(s1, m);
      s2 += __shfl_xor(s2, m);
      s3 += __shfl_xor(s3, m);
    }
    if ((lane & 15) == 0) {
      int row = rbase + mi * 16 + (lane >> 4) * 4;
      atomicAdd(&down[row + 0], s0);
      atomicAdd(&down[row + 1], s1);
      atomicAdd(&down[row + 2], s2);
      atomicAdd(&down[row + 3], s3);
    }
  }
}

// ---------------- kernel 4: up = exp(EN.DE/tau); out += up/down  (fp32 exact)
__global__ void finalize_kernel(const float* __restrict__ EN, const float* __restrict__ DE,
                                const float* __restrict__ down, float* __restrict__ out) {
  __shared__ float red[4][64];
  const int r0 = blockIdx.x * 64;
  const int b  = r0 >> 9;
  const int l0 = r0 & 511;
  const int t  = threadIdx.x;
  const int ll = t & 63;
  const int g  = t >> 6;
  float p = 0.f;
  const int ebase = g * 128;
#pragma unroll 4
  for (int e = 0; e < 128; ++e) {
    size_t idx = (size_t)(b * 512 + ebase + e) * 512 + l0 + ll;
    p += EN[idx] * DE[idx];
  }
  red[g][ll] = p;
  __syncthreads();
  if (t < 64) {
    float s = red[0][t] + red[1][t] + red[2][t] + red[3][t];
    float val = __expf(INV_TAU * s) / down[r0 + t];
#pragma unroll
    for (int m = 1; m <= 32; m <<= 1) val += __shfl_xor(val, m);
    if (t == 0) atomicAdd(out, val);
  }
}

extern "C" void kernel_launch(void* const* d_in, const int* in_sizes, int n_in,
                              void* d_out, int out_size, void* d_ws, size_t ws_size,
                              hipStream_t stream) {
  const float* EN = (const float*)d_in[0];
  const float* DE = (const float*)d_in[1];
  const float* M  = (const float*)d_in[2];

  // ws layout: down[2048] f32 | A16 [2048*512] f16 | B16 [32000*512] f16
  float* down = (float*)d_ws;
  f16* A16 = (f16*)((char*)d_ws + 8192);
  f16* B16 = (f16*)((char*)d_ws + 8192 + (size_t)RDIM * EDIM * 2);
  const size_t need = 8192 + (size_t)RDIM * EDIM * 2 + (size_t)VDIM * EDIM * 2;

  hipMemsetAsync(d_out, 0, sizeof(float), stream);
  if (ws_size < need) return;
  hipMemsetAsync(d_ws, 0, RDIM * sizeof(float), stream);

  cvtA_kernel<<<dim3(8, 8, 4), 256, 0, stream>>>(DE, A16);
  cvtM_kernel<<<2048, 256, 0, stream>>>(M, B16);
  gemm_kernel<<<1000, 512, 0, stream>>>(A16, B16, down);
  finalize_kernel<<<32, 256, 0, stream>>>(EN, DE, down, (float*)d_out);
}

// Round 8
// 120.230 us; speedup vs baseline: 1.3518x; 1.3518x over previous
//
#include <hip/hip_runtime.h>

using f16   = _Float16;
using f16x4 = __attribute__((ext_vector_type(4))) _Float16;
using f16x8 = __attribute__((ext_vector_type(8))) _Float16;
using f32x4 = __attribute__((ext_vector_type(4))) float;

#define BDIM 4
#define EDIM 512
#define LDIM 512
#define VDIM 32000
#define RDIM 2048            // B*L
#define INV_TAU 0.1f

using gcvoid = const __attribute__((address_space(1))) void;
using lvoid  = __attribute__((address_space(3))) void;

__device__ __forceinline__ void gload_lds16(const void* g, void* l) {
  __builtin_amdgcn_global_load_lds((gcvoid*)g, (lvoid*)l, 16, 0, 0);
}

// ---------------- kernel 1: DE [B,E,L] f32 -> A16 [R=B*L][E] f16 (transpose+convert)
__global__ void cvtA_kernel(const float* __restrict__ DE, f16* __restrict__ A16) {
  __shared__ float tile[64][65];
  const int b  = blockIdx.z;
  const int e0 = blockIdx.y * 64;
  const int l0 = blockIdx.x * 64;
  const int t  = threadIdx.x;
#pragma unroll
  for (int i = 0; i < 4; ++i) {
    int idx = t + i * 256;
    int el  = idx >> 4;
    int l4  = (idx & 15) * 4;
    float4 v = *reinterpret_cast<const float4*>(
        DE + (size_t)(b * 512 + e0 + el) * 512 + l0 + l4);
    tile[el][l4 + 0] = v.x;
    tile[el][l4 + 1] = v.y;
    tile[el][l4 + 2] = v.z;
    tile[el][l4 + 3] = v.w;
  }
  __syncthreads();
#pragma unroll
  for (int i = 0; i < 4; ++i) {
    int idx = t + i * 256;
    int ll  = idx >> 4;
    int e4  = (idx & 15) * 4;
    f16x4 h;
    h[0] = (f16)tile[e4 + 0][ll];
    h[1] = (f16)tile[e4 + 1][ll];
    h[2] = (f16)tile[e4 + 2][ll];
    h[3] = (f16)tile[e4 + 3][ll];
    *reinterpret_cast<f16x4*>(A16 + (size_t)(b * 512 + l0 + ll) * 512 + e0 + e4) = h;
  }
}

// ---------------- kernel 2: M [V,E] f32 -> B16 [V][E] f16 (stream convert)
__global__ void cvtM_kernel(const float* __restrict__ M, f16* __restrict__ B16) {
  const size_t N4 = (size_t)VDIM * EDIM / 4;
  const size_t stride = (size_t)gridDim.x * blockDim.x;
  for (size_t i = (size_t)blockIdx.x * blockDim.x + threadIdx.x; i < N4; i += stride) {
    float4 v = reinterpret_cast<const float4*>(M)[i];
    f16x4 h = { (f16)v.x, (f16)v.y, (f16)v.z, (f16)v.w };
    reinterpret_cast<f16x4*>(B16)[i] = h;
  }
}

// ---------------- kernel 3: fused GEMM + exp + vocab-sum
// R3's verified structure (90us, 0 conflicts, replay-stable) with ring-3:
// 128x128 tile, BK=32, 16 K-tiles, 3-deep LDS ring (3 x 16KB = 48KB ->
// 3 blocks/CU for cross-block MFMA/stall overlap, the m114 mechanism).
// Counted vmcnt: stage K(t+2) during t (4 loads/wave); boundary
// s_waitcnt vmcnt(4) lgkmcnt(0) (t<=13), vmcnt(0) at t=14.
// Granule swizzle both sides (verified involution): LDS granule g of row r
// holds global k-chunk g ^ ((r>>1)&3).
__global__ __launch_bounds__(256, 3) void gemm_kernel(const f16* __restrict__ A16,
                                                      const f16* __restrict__ B16,
                                                      float* __restrict__ down) {
  __shared__ __align__(16) char sm[3][16384];   // per buf: A[128][32] | B[128][32] f16
  const int orig = blockIdx.x;                  // 4000 blocks = 8 * 500 (bijective)
  const int bid  = (orig & 7) * 500 + (orig >> 3);
  const int rt   = bid & 15;                    // 16 row tiles
  const int ct   = bid >> 4;                    // 250 col tiles
  const int r0   = rt * 128, c0 = ct * 128;
  const int tid  = threadIdx.x;
  const int lane = tid & 63;
  const int w    = tid >> 6;
  const int wr   = w >> 1, wc = w & 1;

  // staging: lane l of instr covers LDS bytes instr*1024 + l*16
  //   row = instr*16 + (l>>2); source k-granule = (l&3) ^ ((l>>3)&3)
  const int srow = lane >> 2;
  const int sel  = ((lane & 3) ^ ((lane >> 3) & 3)) * 8;   // f16 elems

  auto stage = [&](int buf, int t) {
    const int kbase = t * 32;
#pragma unroll
    for (int i = 0; i < 2; ++i) {
      int instr = w * 2 + i;                    // 8 instrs cover 128 rows
      gload_lds16(A16 + (size_t)(r0 + instr * 16 + srow) * 512 + kbase + sel,
                  &sm[buf][instr * 1024]);
    }
#pragma unroll
    for (int i = 0; i < 2; ++i) {
      int instr = w * 2 + i;
      gload_lds16(B16 + (size_t)(c0 + instr * 16 + srow) * 512 + kbase + sel,
                  &sm[buf][8192 + instr * 1024]);
    }
  };

  f32x4 acc[4][4] = {};

  // prologue: fill 2 ring slots (8 loads/wave), wait K0 (oldest 4) landed
  stage(0, 0);
  stage(1, 1);
  asm volatile("s_waitcnt vmcnt(4)" ::: "memory");
  __builtin_amdgcn_s_barrier();
  asm volatile("" ::: "memory");

  // swizzled read granule: kc = lane>>4, row bits 1-2 = (lane>>1)&3
  const int koff = (((lane >> 4) ^ ((lane >> 1) & 3)) * 16);
  const int arow = (wr * 64 + (lane & 15)) * 64;
  const int brow = (wc * 64 + (lane & 15)) * 64;

#pragma unroll
  for (int t = 0; t < 16; ++t) {
    const int cur = t % 3;
    f16x8 af[4], bf[4];
#pragma unroll
    for (int mi = 0; mi < 4; ++mi)
      af[mi] = *reinterpret_cast<const f16x8*>(&sm[cur][arow + mi * 1024 + koff]);
#pragma unroll
    for (int ni = 0; ni < 4; ++ni)
      bf[ni] = *reinterpret_cast<const f16x8*>(&sm[cur][8192 + brow + ni * 1024 + koff]);

    if (t + 2 < 16) stage((t + 2) % 3, t + 2);

    __builtin_amdgcn_s_setprio(1);
#pragma unroll
    for (int mi = 0; mi < 4; ++mi)
#pragma unroll
      for (int ni = 0; ni < 4; ++ni)
        acc[mi][ni] = __builtin_amdgcn_mfma_f32_16x16x32_f16(
            af[mi], bf[ni], acc[mi][ni], 0, 0, 0);
    __builtin_amdgcn_s_setprio(0);

    if (t < 15) {
      // in flight after stage at t: K(t+1) 4 + K(t+2) 4 -> vmcnt(4) proves
      // K(t+1). At t=14 nothing new staged; only K15's 4 remain -> vmcnt(0).
      // lgkmcnt(0) closes the ring-slot WAR ((t+2)%3 == (t-1)%3).
      if (t <= 13) asm volatile("s_waitcnt vmcnt(4) lgkmcnt(0)" ::: "memory");
      else         asm volatile("s_waitcnt vmcnt(0) lgkmcnt(0)" ::: "memory");
      __builtin_amdgcn_s_barrier();
      asm volatile("" ::: "memory");
    }
  }

  // epilogue: exp + sum over this wave's 64 columns, then atomic into down[]
  // D layout: col = lane&15, row = (lane>>4)*4 + j  (m89-verified)
  const int rbase = r0 + wr * 64;
#pragma unroll
  for (int mi = 0; mi < 4; ++mi) {
    float s0 = 0.f, s1 = 0.f, s2 = 0.f, s3 = 0.f;
#pragma unroll
    for (int ni = 0; ni < 4; ++ni) {
      f32x4 v = acc[mi][ni];
      s0 += __expf(INV_TAU * v[0]);
      s1 += __expf(INV_TAU * v[1]);
      s2 += __expf(INV_TAU * v[2]);
      s3 += __expf(INV_TAU * v[3]);
    }
#pragma unroll
    for (int m = 1; m <= 8; m <<= 1) {
      s0 += __shfl_xor(s0, m);
      s1 += __shfl_xor(s1, m);
      s2 += __shfl_xor(s2, m);
      s3 += __shfl_xor(s3, m);
    }
    if ((lane & 15) == 0) {
      int row = rbase + mi * 16 + (lane >> 4) * 4;
      atomicAdd(&down[row + 0], s0);
      atomicAdd(&down[row + 1], s1);
      atomicAdd(&down[row + 2], s2);
      atomicAdd(&down[row + 3], s3);
    }
  }
}

// ---------------- kernel 4a: partial[r] += sum over one e-octant of EN.DE
// 256 blocks = 32 l-groups x 8 e-octants (vs old 32 blocks: was per-CU-BW
// latency-bound at ~20us; now ~3us). Coalesced: 64 consecutive l per lane.
__global__ void partial_kernel(const float* __restrict__ EN, const float* __restrict__ DE,
                               float* __restrict__ partial) {
  __shared__ float red[4][64];
  const int bk = blockIdx.x;
  const int r0 = (bk & 31) * 64;            // row group (b*512+l), 32 groups
  const int eo = (bk >> 5) * 64;            // e-octant base
  const int b  = r0 >> 9;
  const int l0 = r0 & 511;
  const int t  = threadIdx.x;
  const int ll = t & 63;
  const int g  = t >> 6;                    // 4 e-subchunks of 16
  float p = 0.f;
  const int ebase = eo + g * 16;
#pragma unroll 4
  for (int e = 0; e < 16; ++e) {
    size_t idx = (size_t)(b * 512 + ebase + e) * 512 + l0 + ll;
    p += EN[idx] * DE[idx];
  }
  red[g][ll] = p;
  __syncthreads();
  if (t < 64) {
    float s = red[0][t] + red[1][t] + red[2][t] + red[3][t];
    atomicAdd(&partial[r0 + t], s);
  }
}

// ---------------- kernel 4b: out = sum_r exp(partial[r]/tau) / down[r]
__global__ void finalize2_kernel(const float* __restrict__ partial,
                                 const float* __restrict__ down,
                                 float* __restrict__ out) {
  __shared__ float red[4];
  const int r = blockIdx.x * 256 + threadIdx.x;
  const int lane = threadIdx.x & 63;
  const int w = threadIdx.x >> 6;
  float val = __expf(INV_TAU * partial[r]) / down[r];
#pragma unroll
  for (int m = 1; m <= 32; m <<= 1) val += __shfl_xor(val, m);
  if (lane == 0) red[w] = val;
  __syncthreads();
  if (threadIdx.x == 0)
    atomicAdd(out, red[0] + red[1] + red[2] + red[3]);
}

extern "C" void kernel_launch(void* const* d_in, const int* in_sizes, int n_in,
                              void* d_out, int out_size, void* d_ws, size_t ws_size,
                              hipStream_t stream) {
  const float* EN = (const float*)d_in[0];
  const float* DE = (const float*)d_in[1];
  const float* M  = (const float*)d_in[2];

  // ws layout: down[2048] f32 | partial[2048] f32 | A16 [2048*512] f16 | B16 [32000*512] f16
  float* down    = (float*)d_ws;
  float* partial = (float*)((char*)d_ws + 8192);
  f16* A16 = (f16*)((char*)d_ws + 16384);
  f16* B16 = (f16*)((char*)d_ws + 16384 + (size_t)RDIM * EDIM * 2);
  const size_t need = 16384 + (size_t)RDIM * EDIM * 2 + (size_t)VDIM * EDIM * 2;

  hipMemsetAsync(d_out, 0, sizeof(float), stream);
  if (ws_size < need) return;
  hipMemsetAsync(d_ws, 0, 16384, stream);    // zero down + partial

  cvtA_kernel<<<dim3(8, 8, 4), 256, 0, stream>>>(DE, A16);
  cvtM_kernel<<<2048, 256, 0, stream>>>(M, B16);
  partial_kernel<<<256, 256, 0, stream>>>(EN, DE, partial);
  gemm_kernel<<<4000, 256, 0, stream>>>(A16, B16, down);
  finalize2_kernel<<<8, 256, 0, stream>>>(partial, down, (float*)d_out);
}